// Round 13
// baseline (158.291 us; speedup 1.0000x reference)
//
#include <hip/hip_runtime.h>
#include <hip/hip_fp16.h>

#define NPOS 784
#define WDIM 28

typedef _Float16 f16x8 __attribute__((ext_vector_type(8)));
typedef _Float16 f16x4 __attribute__((ext_vector_type(4)));
typedef float    f32x4 __attribute__((ext_vector_type(4)));

// ---------------- kernel 1: prep (r8 structure, unchanged) ----------------
__global__ __launch_bounds__(256) void prep_kernel(
    const float* __restrict__ x,
    const float* __restrict__ wk, const float* __restrict__ bk,
    const float* __restrict__ wv, const float* __restrict__ bv,
    const float* __restrict__ w_out,
    const float* __restrict__ rw1, const float* __restrict__ rb1,
    const float* __restrict__ rga, const float* __restrict__ rbe,
    const float* __restrict__ rw2, const float* __restrict__ rb2,
    const float* __restrict__ cw1, const float* __restrict__ cb1,
    const float* __restrict__ cga, const float* __restrict__ cbe,
    const float* __restrict__ cw2, const float* __restrict__ cb2,
    _Float16* __restrict__ Kfrag, _Float16* __restrict__ Vfrag,
    _Float16* __restrict__ Wfrag,
    float* __restrict__ Etr, float* __restrict__ Etc)
{
    const int t = threadIdx.x;
    if (blockIdx.x == 416) {                         // ---- embed path ----
        int d = -1;
        const float *w1 = rw1, *b1 = rb1, *ga = rga, *be = rbe, *w2 = rw2, *b2 = rb2;
        float* E = Etr;
        if (t < 110) { d = t; }
        else if (t >= 128 && t < 238) { d = t - 128; w1 = cw1; b1 = cb1; ga = cga; be = cbe; w2 = cw2; b2 = cb2; E = Etc; }
        if (d < 0) return;
        float u = (d < 55) ? (-1.0f + (float)d * (2.0f / 54.0f))
                           : -(-1.0f + (float)(d - 55) * (2.0f / 54.0f));
        float hb[16], mu = 0.0f;
#pragma unroll
        for (int c = 0; c < 16; ++c) { hb[c] = u * w1[c] + b1[c]; mu += hb[c]; }
        mu *= (1.0f / 16.0f);
        float var = 0.0f;
#pragma unroll
        for (int c = 0; c < 16; ++c) { float dv = hb[c] - mu; var += dv * dv; }
        var *= (1.0f / 16.0f);
        float rstd = rsqrtf(var + 1e-5f);
#pragma unroll
        for (int c = 0; c < 16; ++c) {
            float hn = ga[c] * (hb[c] - mu) * rstd + be[c];
            hb[c] = hn / (1.0f + __expf(-hn));
        }
#pragma unroll
        for (int m = 0; m < 8; ++m) {
            float e = b2[m];
#pragma unroll
            for (int c = 0; c < 16; ++c) e += hb[c] * w2[m * 16 + c];
            E[m * 110 + d] = e;
        }
        return;
    }
    if (blockIdx.x == 417) {                         // ---- Wfrag build ----
        for (int idx = t; idx < 8192; idx += 256) {
            int obc = idx >> 9, lane = (idx >> 3) & 63, j = idx & 7;
            int o  = (obc >> 2) * 16 + (lane & 15);
            int mh = (obc & 3) * 32 + (lane >> 4) * 8 + j;
            Wfrag[idx] = (_Float16)w_out[o * 128 + mh];
        }
        return;
    }

    // ---- k/v path: blocks 0..415 = (b, ij-tile of 64, h) ----
    const int bid  = blockIdx.x;
    const int b    = bid / 104, rem = bid - b * 104;
    const int tile = rem >> 3, h = rem & 7;
    const int lane = t & 63, mg = t >> 6;            // wave = m-group {4mg..4mg+3}
    const int bh   = b * 8 + h;

    // zero-fill pads (all 256 threads, BEFORE the ij guard)
    {
        if (t < 128) {                               // Kfrag contraction pad lanes 32..63
            int sub = (t >> 5) & 3, l32 = 32 + (t & 31);
            int qz = tile * 4 + sub;
            if (qz < 49)
                *(f16x8*)(Kfrag + ((size_t)(bh * 49 + qz) * 64 + l32) * 8) = (f16x8){};
        }
        if (tile == 12 && t < 32)                    // Vfrag pad keys 784..799
            *(f16x8*)(Vfrag + ((size_t)(bh * 25 + 24) * 64 + 32 + t) * 8) = (f16x8){};
    }

    const int ij = tile * 64 + lane;
    if (ij >= NPOS) return;

    float x0 = x[(b * 3 + 0) * NPOS + ij];
    float x1 = x[(b * 3 + 1) * NPOS + ij];
    float x2 = x[(b * 3 + 2) * NPOS + ij];

    float4 kv;
    float vv[4];
#pragma unroll
    for (int j = 0; j < 4; ++j) {
        int m = mg * 4 + j, oc = m * 8 + h;          // wave-uniform weight loads
        float w0, w1, w2v;
        w0 = wk[oc*3+0]; w1 = wk[oc*3+1]; w2v = wk[oc*3+2];
        ((float*)&kv)[j] = bk[oc] + w0*x0 + w1*x1 + w2v*x2;
        w0 = wv[oc*3+0]; w1 = wv[oc*3+1]; w2v = wv[oc*3+2];
        vv[j] = bv[oc] + w0*x0 + w1*x1 + w2v*x2;
    }
    // Kfrag: element [bh][ij>>4][lane'][m&7] = K(q=ij, m), lane' = (m>>3)<<4 | (ij&15)
    {
        int qt = ij >> 4;
        int lp = ((mg >> 1) << 4) | (ij & 15);
        int jb = (mg & 1) * 4;
        f16x4 k4 = {(_Float16)kv.x, (_Float16)kv.y, (_Float16)kv.z, (_Float16)kv.w};
        *(f16x4*)(Kfrag + ((size_t)(bh * 49 + qt) * 64 + lp) * 8 + jb) = k4;
    }
    // Vfrag: element [bh][ij>>5][((kk>>3)<<4)|m][kk&7] = V(k=ij, m)
    {
        int s5 = ij >> 5, kk = ij & 31;
        _Float16* vb = Vfrag + (((size_t)(bh * 25 + s5) * 64 + ((kk >> 3) << 4)) << 3) + (kk & 7);
#pragma unroll
        for (int j = 0; j < 4; ++j) vb[(mg * 4 + j) * 8] = (_Float16)vv[j];
    }
}

// ---------------- kernel 2: attention, key-split wave pairs (r12 machinery) ----------------
// Grid = 196 blocks (b, qtile of 16), 1024 thr = 16 waves = (hf, h); waves h and
// h+8 split the V-chunks by parity (pv = hf, hf+2, ...) -> 4 waves/SIMD.
// vs r9: launch_bounds(1024,4) (r9's (1024,1) made the compiler pick 64 VGPR and
// SPILL), no runtime-indexed arrays, r8's single-buffer ptile (r12 proved dbuf
// worthless), e-MFMA denominator (partials combine with d in one LDS publish),
// component-split tab build.
// LDS: [0,56320) tab; [56320,+84992) union{ ebuf | ptile 16w x 2592h |
//      ovh[0,17408) + dbuf[17408,84992) }; [141312,+1024) mxbuf. total 142336.
#define UNI_OFF 56320
#define DB_OFF  17408
#define MX_OFF  141312
__global__ __launch_bounds__(1024, 4) void attn_kernel(
    const _Float16* __restrict__ Kfrag, const _Float16* __restrict__ Vfrag,
    const _Float16* __restrict__ Wfrag,
    const float* __restrict__ Etr, const float* __restrict__ Etc,
    const float* __restrict__ x,
    const float* __restrict__ wq, const float* __restrict__ bq,
    const float* __restrict__ b_out, float* __restrict__ out)
{
    __shared__ __align__(16) unsigned char smem[142336];
    const int t = threadIdx.x, wave = t >> 6, lane = t & 63;
    const int q15 = lane & 15, rg = lane >> 4;
    const int h = wave & 7, hf = wave >> 3;

    // bijective chunked XCD swizzle (196 = 4*25 + 4*24)
    int bid = blockIdx.x;
    int xcd = bid & 7;
    int lb  = ((xcd < 4) ? xcd * 25 : 100 + (xcd - 4) * 24) + (bid >> 3);
    const int b = lb / 49, qt = lb - b * 49;
    const int bh = b * 8 + h;
    const int q_ij = qt * 16 + q15;                   // this lane's query (its S-col)
    const int iq = q_ij / WDIM, jq = q_ij % WDIM;
    const float scale = 0.57735026918962576f;         // 1/sqrt(CIN=3)

    // ---- stage embed tables into LDS (block-shared) ----
    float* ebuf = (float*)(smem + UNI_OFF);
    for (int i = t; i < 1760; i += 1024) ebuf[i] = (i < 880) ? Etr[i] : Etc[i - 880];

    // ---- q on the fly (both halves compute their h's q; cheap duplicate) ----
    float ql[8], qh[8];
    {
        float x0 = x[(b * 3 + 0) * NPOS + q_ij];
        float x1 = x[(b * 3 + 1) * NPOS + q_ij];
        float x2 = x[(b * 3 + 2) * NPOS + q_ij];
#pragma unroll
        for (int m = 0; m < 8; ++m) {
            int oc = m * 8 + h;                       // wave-uniform weights
            ql[m] = bq[oc] + wq[oc*3+0]*x0 + wq[oc*3+1]*x1 + wq[oc*3+2]*x2;
        }
#pragma unroll
        for (int m = 0; m < 8; ++m) {
            int oc = (m + 8) * 8 + h;
            qh[m] = bq[oc] + wq[oc*3+0]*x0 + wq[oc*3+1]*x1 + wq[oc*3+2]*x2;
        }
    }
    f16x8 qf = {};                                    // B-frag: rows m, cols q; m>=16 pad
    if (rg == 0) {
#pragma unroll
        for (int j = 0; j < 8; ++j) qf[j] = (_Float16)ql[j];
    } else if (rg == 1) {
#pragma unroll
        for (int j = 0; j < 8; ++j) qf[j] = (_Float16)qh[j];
    }
    __syncthreads();                                  // B1: ebuf ready

    // ---- tab build, component-split across the wave pair (r9-proven piece) ----
    // hf=0 builds (er,ec) -> tab[dd].x ; hf=1 builds (er5,ec5) -> tab[dd].y
    {
        unsigned int* tab32 = (unsigned int*)smem + (h * 16 + q15) * 110;
        const int d5 = hf * 55;
        float m1 = -3.0e38f, m2 = -3.0e38f;
        for (int tv = 0; tv < 14; ++tv) {
            int dd = rg * 14 + tv;
            if (dd < 55) {
                float a1 = 0, a2 = 0;
#pragma unroll
                for (int mm = 0; mm < 8; ++mm) {
                    a1 += ql[mm] * ebuf[mm * 110 + dd + d5];
                    a2 += qh[mm] * ebuf[880 + mm * 110 + dd + d5];
                }
                m1 = fmaxf(m1, a1); m2 = fmaxf(m2, a2);
            }
        }
        m1 = fmaxf(m1, __shfl_xor(m1, 16, 64)); m1 = fmaxf(m1, __shfl_xor(m1, 32, 64));
        m2 = fmaxf(m2, __shfl_xor(m2, 16, 64)); m2 = fmaxf(m2, __shfl_xor(m2, 32, 64));
        for (int tv = 0; tv < 14; ++tv) {
            int dd = rg * 14 + tv;
            if (dd < 55) {
                float a1 = 0, a2 = 0;
#pragma unroll
                for (int mm = 0; mm < 8; ++mm) {
                    a1 += ql[mm] * ebuf[mm * 110 + dd + d5];
                    a2 += qh[mm] * ebuf[880 + mm * 110 + dd + d5];
                }
                __half2 hp = __floats2half2_rn(__expf(scale * (a1 - m1)),
                                               __expf(scale * (a2 - m2)));
                tab32[dd * 2 + hf] = *(unsigned int*)&hp;
            }
        }
    }
    __syncthreads();                                  // B2: tab complete (pair-shared)

    const f16x8* kchunk = (const f16x8*)(Kfrag + (size_t)bh * 49 * 64 * 8);

    // ---- pass 1: per-query max over this half's chunks, then pair-combine ----
    float mx = -3.0e38f;
    for (int pv = hf; pv < 25; pv += 2) {
#pragma unroll
        for (int c2 = 0; c2 < 2; ++c2) {
            int ch = 2 * pv + c2;
            if (ch < 49) {
                f16x8 kf = kchunk[ch * 64 + lane];
                f32x4 s = __builtin_amdgcn_mfma_f32_16x16x32_f16(kf, qf, (f32x4){0,0,0,0}, 0, 0, 0);
                mx = fmaxf(mx, fmaxf(fmaxf(s[0], s[1]), fmaxf(s[2], s[3])));
            }
        }
    }
    mx = fmaxf(mx, __shfl_xor(mx, 16, 64));
    mx = fmaxf(mx, __shfl_xor(mx, 32, 64));
    float* mxbuf = (float*)(smem + MX_OFF);
    if (rg == 0) mxbuf[wave * 16 + q15] = mx;
    __syncthreads();                                  // B3: max exchange
    mx = fmaxf(mx, mxbuf[(wave ^ 8) * 16 + q15]);
    const float c1  = 0.57735026918962576f * 1.44269504088896341f;  // scale*log2e
    const float c2f = 6.0f - mx * c1;                 // +6: p *= 64 (exact, cancels)

    // ---- pass 2: this half's chunks; single-buffer ptile (r8 proven) ----
    f32x4 d0 = {0,0,0,0}, d1 = {0,0,0,0}, d2 = {0,0,0,0}, d3 = {0,0,0,0};
    f32x4 e0 = {0,0,0,0}, e1 = {0,0,0,0}, e2 = {0,0,0,0}, e3 = {0,0,0,0};
    _Float16* ptw = (_Float16*)(smem + UNI_OFF) + (size_t)wave * 2592;
    const uint2* tab = (const uint2*)smem + (h * 16 + q15) * 55;
    const int prow  = (q15 & 3) * 4;                  // my q's PV-A row base (its tile)
    const int tbase = (q15 >> 2) * 648;               // my q's PV-A tile offset (halves)
    const int rof   = q15 * 40 + rg * 8;              // A-frag read offset within a tile
    const f16x8* vbase = (const f16x8*)(Vfrag + (size_t)bh * 25 * 64 * 8);
    f16x8 onesB;
#pragma unroll
    for (int j = 0; j < 8; ++j) onesB[j] = (_Float16)1.0f;

    f16x8 kfA = kchunk[(2 * hf) * 64 + lane];
    f16x8 kfB = kchunk[(2 * hf + 1) * 64 + lane];
    f16x8 bf  = vbase[hf * 64 + lane];
    for (int pv = hf; pv < 25; pv += 2) {
        int pvn = pv + 2;
        int nA = (2 * pvn     < 49) ? 2 * pvn     : 48;
        int nB = (2 * pvn + 1 < 49) ? 2 * pvn + 1 : 48;
        int nV = (pvn < 25) ? pvn : 24;
        f16x8 kfA2 = kchunk[nA * 64 + lane];
        f16x8 kfB2 = kchunk[nB * 64 + lane];
        f16x8 bf2  = vbase[nV * 64 + lane];
#pragma unroll
        for (int c2 = 0; c2 < 2; ++c2) {
            int ch = 2 * pv + c2;
            int cb = rg * 4 + c2 * 16;                // 4 consecutive key-cols
            if (ch < 49) {
                f16x8 kf = c2 ? kfB : kfA;
                f32x4 s = __builtin_amdgcn_mfma_f32_16x16x32_f16(kf, qf, (f32x4){0,0,0,0}, 0, 0, 0);
                float pg[4][4];
#pragma unroll
                for (int reg = 0; reg < 4; ++reg) {
                    float ec = exp2f(s[reg] * c1 + c2f);
                    int k = ch * 16 + rg * 4 + reg;   // D row = key
                    int rk = (k * 2341) >> 16;        // k/28, exact for k<784
                    int ck = k - rk * WDIM;
                    uint2 tr = tab[rk - iq + 27];
                    uint2 tc = tab[ck - jq + 27];
                    float2 r01 = __half22float2(*(__half2*)&tr.x);
                    float2 r23 = __half22float2(*(__half2*)&tr.y);
                    float2 c01 = __half22float2(*(__half2*)&tc.x);
                    float2 c23 = __half22float2(*(__half2*)&tc.y);
                    pg[0][reg] = ec * r01.x * c01.y;  // g-mapping carried from r4 (verified)
                    pg[1][reg] = ec * r01.y * c23.x;
                    pg[2][reg] = ec * r23.x * c23.y;
                    pg[3][reg] = ec * r23.y * c01.x;
                }
#pragma unroll
                for (int g = 0; g < 4; ++g) {
                    __half2 a01 = __floats2half2_rn(pg[g][0], pg[g][1]);
                    __half2 a23 = __floats2half2_rn(pg[g][2], pg[g][3]);
                    uint2 w; w.x = *(unsigned int*)&a01; w.y = *(unsigned int*)&a23;
                    *(uint2*)(ptw + tbase + (prow + g) * 40 + cb) = w;
                }
            } else {
                uint2 w; w.x = 0u; w.y = 0u;
#pragma unroll
                for (int g = 0; g < 4; ++g)
                    *(uint2*)(ptw + tbase + (prow + g) * 40 + cb) = w;
            }
        }
        // PV + denominator MFMAs (same-wave DS in-order: reads see the writes)
        f16x8 aA = *(const f16x8*)(ptw + 0 * 648 + rof);
        f16x8 aB = *(const f16x8*)(ptw + 1 * 648 + rof);
        f16x8 aC = *(const f16x8*)(ptw + 2 * 648 + rof);
        f16x8 aD = *(const f16x8*)(ptw + 3 * 648 + rof);
        __builtin_amdgcn_s_setprio(1);
        d0 = __builtin_amdgcn_mfma_f32_16x16x32_f16(aA, bf, d0, 0, 0, 0);
        e0 = __builtin_amdgcn_mfma_f32_16x16x32_f16(aA, onesB, e0, 0, 0, 0);
        d1 = __builtin_amdgcn_mfma_f32_16x16x32_f16(aB, bf, d1, 0, 0, 0);
        e1 = __builtin_amdgcn_mfma_f32_16x16x32_f16(aB, onesB, e1, 0, 0, 0);
        d2 = __builtin_amdgcn_mfma_f32_16x16x32_f16(aC, bf, d2, 0, 0, 0);
        e2 = __builtin_amdgcn_mfma_f32_16x16x32_f16(aC, onesB, e2, 0, 0, 0);
        d3 = __builtin_amdgcn_mfma_f32_16x16x32_f16(aD, bf, d3, 0, 0, 0);
        e3 = __builtin_amdgcn_mfma_f32_16x16x32_f16(aD, onesB, e3, 0, 0, 0);
        __builtin_amdgcn_s_setprio(0);
        kfA = kfA2; kfB = kfB2; bf = bf2;
    }

    __syncthreads();                                  // B4: all ptile use done
    // ---- cross-half combine: hf=1 publishes d/e, hf=0 accumulates ----
    float* dbuf = (float*)(smem + UNI_OFF + DB_OFF);
    if (hf) {
        float* ds = dbuf + h * (64 * 33) + lane * 33; // stride 33: conflict-free
        ds[0]=d0[0];  ds[1]=d0[1];  ds[2]=d0[2];  ds[3]=d0[3];
        ds[4]=d1[0];  ds[5]=d1[1];  ds[6]=d1[2];  ds[7]=d1[3];
        ds[8]=d2[0];  ds[9]=d2[1];  ds[10]=d2[2]; ds[11]=d2[3];
        ds[12]=d3[0]; ds[13]=d3[1]; ds[14]=d3[2]; ds[15]=d3[3];
        ds[16]=e0[0]; ds[17]=e0[1]; ds[18]=e0[2]; ds[19]=e0[3];
        ds[20]=e1[0]; ds[21]=e1[1]; ds[22]=e1[2]; ds[23]=e1[3];
        ds[24]=e2[0]; ds[25]=e2[1]; ds[26]=e2[2]; ds[27]=e2[3];
        ds[28]=e3[0]; ds[29]=e3[1]; ds[30]=e3[2]; ds[31]=e3[3];
    }
    __syncthreads();                                  // B5: partials published
    // ---- epilogue (hf=0): combine, normalize, write ovh (disjoint from dbuf) ----
    _Float16* ovh = (_Float16*)(smem + UNI_OFF);
    if (!hf) {
        const float* ds = dbuf + h * (64 * 33) + lane * 33;
        d0[0]+=ds[0];  d0[1]+=ds[1];  d0[2]+=ds[2];  d0[3]+=ds[3];
        d1[0]+=ds[4];  d1[1]+=ds[5];  d1[2]+=ds[6];  d1[3]+=ds[7];
        d2[0]+=ds[8];  d2[1]+=ds[9];  d2[2]+=ds[10]; d2[3]+=ds[11];
        d3[0]+=ds[12]; d3[1]+=ds[13]; d3[2]+=ds[14]; d3[3]+=ds[15];
        e0[0]+=ds[16]; e0[1]+=ds[17]; e0[2]+=ds[18]; e0[3]+=ds[19];
        e1[0]+=ds[20]; e1[1]+=ds[21]; e1[2]+=ds[22]; e1[3]+=ds[23];
        e2[0]+=ds[24]; e2[1]+=ds[25]; e2[2]+=ds[26]; e2[3]+=ds[27];
        e3[0]+=ds[28]; e3[1]+=ds[29]; e3[2]+=ds[30]; e3[3]+=ds[31];
        int mo = q15 * 8 + h;                         // m = q15 (D col), h
#pragma unroll
        for (int reg = 0; reg < 4; ++reg) {           // reg = g; q = 4*tile + rg
            float i0 = (e0[reg] > 0.0f) ? 1.0f / e0[reg] : 0.0f;
            float i1 = (e1[reg] > 0.0f) ? 1.0f / e1[reg] : 0.0f;
            float i2 = (e2[reg] > 0.0f) ? 1.0f / e2[reg] : 0.0f;
            float i3 = (e3[reg] > 0.0f) ? 1.0f / e3[reg] : 0.0f;
            ovh[(reg * 16 +      rg) * 136 + mo] = (_Float16)(d0[reg] * i0);
            ovh[(reg * 16 +  4 + rg) * 136 + mo] = (_Float16)(d1[reg] * i1);
            ovh[(reg * 16 +  8 + rg) * 136 + mo] = (_Float16)(d2[reg] * i2);
            ovh[(reg * 16 + 12 + rg) * 136 + mo] = (_Float16)(d3[reg] * i3);
        }
    }
    __syncthreads();                                  // B6: ovh ready

    // ---- output projection via MFMA: 16 waves x one (ob,g) tile ----
    {
        int ob = wave >> 2, g = wave & 3;
        f32x4 dd = {0,0,0,0};
#pragma unroll
        for (int c = 0; c < 4; ++c) {
            f16x8 wa = *(const f16x8*)(Wfrag + ((size_t)((ob * 4 + c) * 64 + lane)) * 8);
            f16x8 vb = *(const f16x8*)(ovh + (g * 16 + q15) * 136 + c * 32 + rg * 8);
            dd = __builtin_amdgcn_mfma_f32_16x16x32_f16(wa, vb, dd, 0, 0, 0);
        }
#pragma unroll
        for (int reg = 0; reg < 4; ++reg) {
            int o = ob * 16 + rg * 4 + reg;           // D row
            out[((size_t)(b * 64 + o) * 4 + g) * NPOS + qt * 16 + q15] = dd[reg] + b_out[o];
        }
    }
}

extern "C" void kernel_launch(void* const* d_in, const int* in_sizes, int n_in,
                              void* d_out, int out_size, void* d_ws, size_t ws_size,
                              hipStream_t stream)
{
    const float* x     = (const float*)d_in[0];
    const float* wq    = (const float*)d_in[1];
    const float* bq    = (const float*)d_in[2];
    const float* wk    = (const float*)d_in[3];
    const float* bk    = (const float*)d_in[4];
    const float* wv    = (const float*)d_in[5];
    const float* bv    = (const float*)d_in[6];
    const float* w_out = (const float*)d_in[7];
    const float* b_out = (const float*)d_in[8];
    const float* rw1 = (const float*)d_in[9];
    const float* rb1 = (const float*)d_in[10];
    const float* rga = (const float*)d_in[11];
    const float* rbe = (const float*)d_in[12];
    const float* rw2 = (const float*)d_in[13];
    const float* rb2 = (const float*)d_in[14];
    const float* cw1 = (const float*)d_in[15];
    const float* cb1 = (const float*)d_in[16];
    const float* cga = (const float*)d_in[17];
    const float* cbe = (const float*)d_in[18];
    const float* cw2 = (const float*)d_in[19];
    const float* cb2 = (const float*)d_in[20];
    // d_in[21]/d_in[22] (ridx/cidx) unused: closed-form rotation indices.

    float* Etr       = (float*)d_ws;                  // 880
    float* Etc       = Etr + 880;                     // 880
    _Float16* Kfrag  = (_Float16*)(Etc + 880);        // 32*49*64*8 = 802816 halves
    _Float16* Vfrag  = Kfrag + 802816;                // 32*25*64*8 = 409600
    _Float16* Wfrag  = Vfrag + 409600;                // 8192

    prep_kernel<<<418, 256, 0, stream>>>(x, wk, bk, wv, bv, w_out,
                                         rw1, rb1, rga, rbe, rw2, rb2,
                                         cw1, cb1, cga, cbe, cw2, cb2,
                                         Kfrag, Vfrag, Wfrag, Etr, Etc);
    attn_kernel<<<196, 1024, 0, stream>>>(Kfrag, Vfrag, Wfrag, Etr, Etc,
                                          x, wq, bq, b_out, (float*)d_out);
}

// Round 14
// 147.063 us; speedup vs baseline: 1.0763x; 1.0763x over previous
//
#include <hip/hip_runtime.h>
#include <hip/hip_fp16.h>

#define NPOS 784
#define WDIM 28

typedef _Float16 f16x8 __attribute__((ext_vector_type(8)));
typedef _Float16 f16x4 __attribute__((ext_vector_type(4)));
typedef float    f32x4 __attribute__((ext_vector_type(4)));

// ---------------- kernel 1: prep ----------------
// Blocks 0..415: k/v fragments (r8 structure).
// Block 416: embed tables E -> LDS -> Efrag: 16 MFMA A-fragments (4 comp x 4
//   dd-chunks) for the attn tab build. comp 0=ar(Etr,dd) 1=ac(Etc,dd)
//   2=ar5(Etr,dd+55) 3=ac5(Etc,dd+55); k rows 0..7 = Etr m, 8..15 = Etc m,
//   16..31 zero; dd>=55 rows zero.
// Block 417: Wfrag.
__global__ __launch_bounds__(256) void prep_kernel(
    const float* __restrict__ x,
    const float* __restrict__ wk, const float* __restrict__ bk,
    const float* __restrict__ wv, const float* __restrict__ bv,
    const float* __restrict__ w_out,
    const float* __restrict__ rw1, const float* __restrict__ rb1,
    const float* __restrict__ rga, const float* __restrict__ rbe,
    const float* __restrict__ rw2, const float* __restrict__ rb2,
    const float* __restrict__ cw1, const float* __restrict__ cb1,
    const float* __restrict__ cga, const float* __restrict__ cbe,
    const float* __restrict__ cw2, const float* __restrict__ cb2,
    _Float16* __restrict__ Kfrag, _Float16* __restrict__ Vfrag,
    _Float16* __restrict__ Wfrag, _Float16* __restrict__ Efrag)
{
    const int t = threadIdx.x;
    if (blockIdx.x == 416) {                         // ---- embed + Efrag path ----
        __shared__ float eb[1760];
        int d = -1, base = 0;
        const float *w1 = rw1, *b1 = rb1, *ga = rga, *be = rbe, *w2 = rw2, *b2 = rb2;
        if (t < 110) { d = t; }
        else if (t >= 128 && t < 238) { d = t - 128; base = 880; w1 = cw1; b1 = cb1; ga = cga; be = cbe; w2 = cw2; b2 = cb2; }
        if (d >= 0) {
            float u = (d < 55) ? (-1.0f + (float)d * (2.0f / 54.0f))
                               : -(-1.0f + (float)(d - 55) * (2.0f / 54.0f));
            float hb[16], mu = 0.0f;
#pragma unroll
            for (int c = 0; c < 16; ++c) { hb[c] = u * w1[c] + b1[c]; mu += hb[c]; }
            mu *= (1.0f / 16.0f);
            float var = 0.0f;
#pragma unroll
            for (int c = 0; c < 16; ++c) { float dv = hb[c] - mu; var += dv * dv; }
            var *= (1.0f / 16.0f);
            float rstd = rsqrtf(var + 1e-5f);
#pragma unroll
            for (int c = 0; c < 16; ++c) {
                float hn = ga[c] * (hb[c] - mu) * rstd + be[c];
                hb[c] = hn / (1.0f + __expf(-hn));
            }
#pragma unroll
            for (int m = 0; m < 8; ++m) {
                float e = b2[m];
#pragma unroll
                for (int c = 0; c < 16; ++c) e += hb[c] * w2[m * 16 + c];
                eb[base + m * 110 + d] = e;
            }
        }
        __syncthreads();
        for (int idx = t; idx < 1024; idx += 256) {  // 16 frags x 64 lanes
            int frag = idx >> 6, lane = idx & 63;
            int comp = frag >> 2, chunk = frag & 3;
            int dd = chunk * 16 + (lane & 15), kg = lane >> 4;
            f16x8 v = {};
            if (dd < 55) {
                int off = (comp & 2) ? dd + 55 : dd;
                if ((comp & 1) == 0 && kg == 0) {    // ar/ar5: k=0..7 <- Etr
#pragma unroll
                    for (int j = 0; j < 8; ++j) v[j] = (_Float16)eb[j * 110 + off];
                } else if ((comp & 1) == 1 && kg == 1) {  // ac/ac5: k=8..15 <- Etc
#pragma unroll
                    for (int j = 0; j < 8; ++j) v[j] = (_Float16)eb[880 + j * 110 + off];
                }
            }
            *(f16x8*)(Efrag + (size_t)idx * 8) = v;
        }
        return;
    }
    if (blockIdx.x == 417) {                         // ---- Wfrag build ----
        for (int idx = t; idx < 8192; idx += 256) {
            int obc = idx >> 9, lane = (idx >> 3) & 63, j = idx & 7;
            int o  = (obc >> 2) * 16 + (lane & 15);
            int mh = (obc & 3) * 32 + (lane >> 4) * 8 + j;
            Wfrag[idx] = (_Float16)w_out[o * 128 + mh];
        }
        return;
    }

    // ---- k/v path: blocks 0..415 = (b, ij-tile of 64, h) ----
    const int bid  = blockIdx.x;
    const int b    = bid / 104, rem = bid - b * 104;
    const int tile = rem >> 3, h = rem & 7;
    const int lane = t & 63, mg = t >> 6;            // wave = m-group {4mg..4mg+3}
    const int bh   = b * 8 + h;

    // zero-fill pads (all 256 threads, BEFORE the ij guard)
    {
        if (t < 128) {                               // Kfrag contraction pad lanes 32..63
            int sub = (t >> 5) & 3, l32 = 32 + (t & 31);
            int qz = tile * 4 + sub;
            if (qz < 49)
                *(f16x8*)(Kfrag + ((size_t)(bh * 49 + qz) * 64 + l32) * 8) = (f16x8){};
        }
        if (tile == 12 && t < 32)                    // Vfrag pad keys 784..799
            *(f16x8*)(Vfrag + ((size_t)(bh * 25 + 24) * 64 + 32 + t) * 8) = (f16x8){};
    }

    const int ij = tile * 64 + lane;
    if (ij >= NPOS) return;

    float x0 = x[(b * 3 + 0) * NPOS + ij];
    float x1 = x[(b * 3 + 1) * NPOS + ij];
    float x2 = x[(b * 3 + 2) * NPOS + ij];

    float4 kv;
    float vv[4];
#pragma unroll
    for (int j = 0; j < 4; ++j) {
        int m = mg * 4 + j, oc = m * 8 + h;          // wave-uniform weight loads
        float w0, w1, w2v;
        w0 = wk[oc*3+0]; w1 = wk[oc*3+1]; w2v = wk[oc*3+2];
        ((float*)&kv)[j] = bk[oc] + w0*x0 + w1*x1 + w2v*x2;
        w0 = wv[oc*3+0]; w1 = wv[oc*3+1]; w2v = wv[oc*3+2];
        vv[j] = bv[oc] + w0*x0 + w1*x1 + w2v*x2;
    }
    // Kfrag: element [bh][ij>>4][lane'][m&7] = K(q=ij, m), lane' = (m>>3)<<4 | (ij&15)
    {
        int qt = ij >> 4;
        int lp = ((mg >> 1) << 4) | (ij & 15);
        int jb = (mg & 1) * 4;
        f16x4 k4 = {(_Float16)kv.x, (_Float16)kv.y, (_Float16)kv.z, (_Float16)kv.w};
        *(f16x4*)(Kfrag + ((size_t)(bh * 49 + qt) * 64 + lp) * 8 + jb) = k4;
    }
    // Vfrag: element [bh][ij>>5][((kk>>3)<<4)|m][kk&7] = V(k=ij, m)
    {
        int s5 = ij >> 5, kk = ij & 31;
        _Float16* vb = Vfrag + (((size_t)(bh * 25 + s5) * 64 + ((kk >> 3) << 4)) << 3) + (kk & 7);
#pragma unroll
        for (int j = 0; j < 4; ++j) vb[(mg * 4 + j) * 8] = (_Float16)vv[j];
    }
}

// ---------------- kernel 2: attention, 16 queries/wave, all-MFMA ----------------
// Grid = 196 blocks (b, qtile of 16), 512 thr, wave = head.  r14 = r12 with the
// rot-table build moved to the matrix core: 32 MFMAs on prebuilt Efrag (pass A
// tracks the exact per-component max, pass B recomputes -- MFMA is bit-stable)
// replace ~1800 FMA + ~1800 LDS reads per wave.  ebuf staging + both its
// barriers deleted (tab write->read is same-wave in-order DS).
// LDS: [0,56320) tab (8 waves x 16 q x 55 x 8B);
//      [56320,+82944) union{ ptile 8w x 2buf x 2592h | ovh }
#define UNI_OFF 56320
__global__ __launch_bounds__(512, 1) void attn_kernel(
    const _Float16* __restrict__ Kfrag, const _Float16* __restrict__ Vfrag,
    const _Float16* __restrict__ Wfrag, const _Float16* __restrict__ Efrag,
    const float* __restrict__ x,
    const float* __restrict__ wq, const float* __restrict__ bq,
    const float* __restrict__ b_out, float* __restrict__ out)
{
    __shared__ __align__(16) unsigned char smem[56320 + 82944];
    const int t = threadIdx.x, wave = t >> 6, lane = t & 63;
    const int q15 = lane & 15, rg = lane >> 4;

    // bijective chunked XCD swizzle (196 = 4*25 + 4*24)
    int bid = blockIdx.x;
    int xcd = bid & 7;
    int lb  = ((xcd < 4) ? xcd * 25 : 100 + (xcd - 4) * 24) + (bid >> 3);
    const int b = lb / 49, qt = lb - b * 49;
    const int bh = b * 8 + wave;
    const int q_ij = qt * 16 + q15;                   // this lane's query (its S-col)
    const int iq = q_ij / WDIM, jq = q_ij % WDIM;
    const float c1 = 0.57735026918962576f * 1.44269504088896341f;  // scale*log2e

    // ---- q on the fly (f32 -> f16 fragment) ----
    float ql[8], qh[8];                               // unroll-only indexing -> regs
    {
        float x0 = x[(b * 3 + 0) * NPOS + q_ij];
        float x1 = x[(b * 3 + 1) * NPOS + q_ij];
        float x2 = x[(b * 3 + 2) * NPOS + q_ij];
#pragma unroll
        for (int m = 0; m < 8; ++m) {
            int oc = m * 8 + wave;                    // wave-uniform weights
            ql[m] = bq[oc] + wq[oc*3+0]*x0 + wq[oc*3+1]*x1 + wq[oc*3+2]*x2;
        }
#pragma unroll
        for (int m = 0; m < 8; ++m) {
            int oc = (m + 8) * 8 + wave;
            qh[m] = bq[oc] + wq[oc*3+0]*x0 + wq[oc*3+1]*x1 + wq[oc*3+2]*x2;
        }
    }
    f16x8 qf = {};                                    // B-frag: rows m, cols q; m>=16 pad
    if (rg == 0) {
#pragma unroll
        for (int j = 0; j < 8; ++j) qf[j] = (_Float16)ql[j];
    } else if (rg == 1) {
#pragma unroll
        for (int j = 0; j < 8; ++j) qf[j] = (_Float16)qh[j];
    }

    // ---- tab build via MFMA: D[dd][q] = E-component dot (r12 semantics) ----
    {
        const f16x8* efr = (const f16x8*)Efrag;
        float tm0 = -3.0e38f, tm1 = -3.0e38f, tm2 = -3.0e38f, tm3 = -3.0e38f;
#pragma unroll
        for (int chunk = 0; chunk < 4; ++chunk) {     // pass A: exact per-comp max
            f32x4 Dr  = __builtin_amdgcn_mfma_f32_16x16x32_f16(efr[(0*4+chunk)*64+lane], qf, (f32x4){0,0,0,0}, 0, 0, 0);
            f32x4 Dc  = __builtin_amdgcn_mfma_f32_16x16x32_f16(efr[(1*4+chunk)*64+lane], qf, (f32x4){0,0,0,0}, 0, 0, 0);
            f32x4 D5r = __builtin_amdgcn_mfma_f32_16x16x32_f16(efr[(2*4+chunk)*64+lane], qf, (f32x4){0,0,0,0}, 0, 0, 0);
            f32x4 D5c = __builtin_amdgcn_mfma_f32_16x16x32_f16(efr[(3*4+chunk)*64+lane], qf, (f32x4){0,0,0,0}, 0, 0, 0);
#pragma unroll
            for (int reg = 0; reg < 4; ++reg) {
                int dd = chunk * 16 + rg * 4 + reg;   // D row = dd
                if (dd < 55) {
                    tm0 = fmaxf(tm0, Dr[reg]);  tm1 = fmaxf(tm1, Dc[reg]);
                    tm2 = fmaxf(tm2, D5r[reg]); tm3 = fmaxf(tm3, D5c[reg]);
                }
            }
        }
        tm0 = fmaxf(tm0, __shfl_xor(tm0, 16, 64)); tm0 = fmaxf(tm0, __shfl_xor(tm0, 32, 64));
        tm1 = fmaxf(tm1, __shfl_xor(tm1, 16, 64)); tm1 = fmaxf(tm1, __shfl_xor(tm1, 32, 64));
        tm2 = fmaxf(tm2, __shfl_xor(tm2, 16, 64)); tm2 = fmaxf(tm2, __shfl_xor(tm2, 32, 64));
        tm3 = fmaxf(tm3, __shfl_xor(tm3, 16, 64)); tm3 = fmaxf(tm3, __shfl_xor(tm3, 32, 64));
        uint2* tabw = (uint2*)smem + (wave * 16 + q15) * 55;
#pragma unroll
        for (int chunk = 0; chunk < 4; ++chunk) {     // pass B: recompute (bit-stable)
            f32x4 Dr  = __builtin_amdgcn_mfma_f32_16x16x32_f16(efr[(0*4+chunk)*64+lane], qf, (f32x4){0,0,0,0}, 0, 0, 0);
            f32x4 Dc  = __builtin_amdgcn_mfma_f32_16x16x32_f16(efr[(1*4+chunk)*64+lane], qf, (f32x4){0,0,0,0}, 0, 0, 0);
            f32x4 D5r = __builtin_amdgcn_mfma_f32_16x16x32_f16(efr[(2*4+chunk)*64+lane], qf, (f32x4){0,0,0,0}, 0, 0, 0);
            f32x4 D5c = __builtin_amdgcn_mfma_f32_16x16x32_f16(efr[(3*4+chunk)*64+lane], qf, (f32x4){0,0,0,0}, 0, 0, 0);
#pragma unroll
            for (int reg = 0; reg < 4; ++reg) {
                int dd = chunk * 16 + rg * 4 + reg;
                if (dd < 55) {
                    __half2 h01 = __floats2half2_rn(exp2f(c1 * (Dr[reg]  - tm0)),
                                                    exp2f(c1 * (Dc[reg]  - tm1)));
                    __half2 h23 = __floats2half2_rn(exp2f(c1 * (D5r[reg] - tm2)),
                                                    exp2f(c1 * (D5c[reg] - tm3)));
                    uint2 w; w.x = *(unsigned int*)&h01; w.y = *(unsigned int*)&h23;
                    tabw[dd] = w;                     // same-wave read later: no barrier
                }
            }
        }
    }

    const f16x8* kchunk = (const f16x8*)(Kfrag + (size_t)bh * 49 * 64 * 8);

    // ---- pass 1: exact per-query max of raw QK dots (independent MFMAs) ----
    float mx = -3.0e38f;
#pragma unroll 7
    for (int ch = 0; ch < 49; ++ch) {
        f16x8 kf = kchunk[ch * 64 + lane];
        f32x4 s = __builtin_amdgcn_mfma_f32_16x16x32_f16(kf, qf, (f32x4){0,0,0,0}, 0, 0, 0);
        mx = fmaxf(mx, fmaxf(fmaxf(s[0], s[1]), fmaxf(s[2], s[3])));
    }
    mx = fmaxf(mx, __shfl_xor(mx, 16, 64));
    mx = fmaxf(mx, __shfl_xor(mx, 32, 64));
    const float c2f = 6.0f - mx * c1;                 // +6: p *= 64 (exact, cancels)

    // ---- pass 2: S -> p -> double-buffered PV A-tiles -> MFMA (prev chunk) ----
    f32x4 d0 = {0,0,0,0}, d1 = {0,0,0,0}, d2 = {0,0,0,0}, d3 = {0,0,0,0};
    f32x4 e0 = {0,0,0,0}, e1 = {0,0,0,0}, e2 = {0,0,0,0}, e3 = {0,0,0,0};  // ps
    _Float16* ptw = (_Float16*)(smem + UNI_OFF) + (size_t)wave * 5184;  // 2 x 2592
    const uint2* tab = (const uint2*)smem + (wave * 16 + q15) * 55;
    const int prow  = (q15 & 3) * 4;                  // my q's PV-A row base (its tile)
    const int tbase = (q15 >> 2) * 648;               // my q's PV-A tile offset (halves)
    const int rof   = q15 * 40 + rg * 8;              // A-frag read offset within a tile
    const f16x8* vbase = (const f16x8*)(Vfrag + (size_t)bh * 25 * 64 * 8);
    f16x8 onesB;
#pragma unroll
    for (int j = 0; j < 8; ++j) onesB[j] = (_Float16)1.0f;

    f16x8 kfA = kchunk[0 * 64 + lane];
    f16x8 kfB = kchunk[1 * 64 + lane];
    f16x8 bfCur = vbase[lane];
    f16x8 bfPrev = {};
    for (int pv = 0; pv < 25; ++pv) {
        _Float16*       wbuf = ptw + (pv & 1) * 2592;
        const _Float16* rbuf = ptw + ((pv & 1) ^ 1) * 2592;
        // issue prev-buf A-fragment reads EARLY (latency hides under p-compute)
        f16x8 aA = *(const f16x8*)(rbuf + 0 * 648 + rof);
        f16x8 aB = *(const f16x8*)(rbuf + 1 * 648 + rof);
        f16x8 aC = *(const f16x8*)(rbuf + 2 * 648 + rof);
        f16x8 aD = *(const f16x8*)(rbuf + 3 * 648 + rof);
        // prefetch next iteration's global fragments (clamped)
        int nA = (pv * 2 + 2 < 49) ? pv * 2 + 2 : 48;
        int nB = (pv * 2 + 3 < 49) ? pv * 2 + 3 : 48;
        int nV = (pv + 1 < 25) ? pv + 1 : 24;
        f16x8 kfA2 = kchunk[nA * 64 + lane];
        f16x8 kfB2 = kchunk[nB * 64 + lane];
        f16x8 bf2  = vbase[nV * 64 + lane];
#pragma unroll
        for (int c2 = 0; c2 < 2; ++c2) {
            int ch = pv * 2 + c2;
            int cb = rg * 4 + c2 * 16;                // 4 consecutive key-cols
            if (ch < 49) {
                f16x8 kf = c2 ? kfB : kfA;
                f32x4 s = __builtin_amdgcn_mfma_f32_16x16x32_f16(kf, qf, (f32x4){0,0,0,0}, 0, 0, 0);
                float pg[4][4];
#pragma unroll
                for (int reg = 0; reg < 4; ++reg) {
                    float ec = exp2f(s[reg] * c1 + c2f);
                    int k = ch * 16 + rg * 4 + reg;   // D row = key
                    int rk = (k * 2341) >> 16;        // k/28, exact for k<784
                    int ck = k - rk * WDIM;
                    uint2 tr = tab[rk - iq + 27];
                    uint2 tc = tab[ck - jq + 27];
                    float2 r01 = __half22float2(*(__half2*)&tr.x);
                    float2 r23 = __half22float2(*(__half2*)&tr.y);
                    float2 c01 = __half22float2(*(__half2*)&tc.x);
                    float2 c23 = __half22float2(*(__half2*)&tc.y);
                    pg[0][reg] = ec * r01.x * c01.y;  // g-mapping carried from r4 (verified)
                    pg[1][reg] = ec * r01.y * c23.x;
                    pg[2][reg] = ec * r23.x * c23.y;
                    pg[3][reg] = ec * r23.y * c01.x;
                }
#pragma unroll
                for (int g = 0; g < 4; ++g) {
                    __half2 a01 = __floats2half2_rn(pg[g][0], pg[g][1]);
                    __half2 a23 = __floats2half2_rn(pg[g][2], pg[g][3]);
                    uint2 w; w.x = *(unsigned int*)&a01; w.y = *(unsigned int*)&a23;
                    *(uint2*)(wbuf + tbase + (prow + g) * 40 + cb) = w;
                }
            } else {
                uint2 w; w.x = 0u; w.y = 0u;
#pragma unroll
                for (int g = 0; g < 4; ++g)
                    *(uint2*)(wbuf + tbase + (prow + g) * 40 + cb) = w;
            }
        }
        // MFMA the PREVIOUS chunk-pair (A-frags read at loop top, long ready)
        if (pv) {
            __builtin_amdgcn_s_setprio(1);
            d0 = __builtin_amdgcn_mfma_f32_16x16x32_f16(aA, bfPrev, d0, 0, 0, 0);
            e0 = __builtin_amdgcn_mfma_f32_16x16x32_f16(aA, onesB,  e0, 0, 0, 0);
            d1 = __builtin_amdgcn_mfma_f32_16x16x32_f16(aB, bfPrev, d1, 0, 0, 0);
            e1 = __builtin_amdgcn_mfma_f32_16x16x32_f16(aB, onesB,  e1, 0, 0, 0);
            d2 = __builtin_amdgcn_mfma_f32_16x16x32_f16(aC, bfPrev, d2, 0, 0, 0);
            e2 = __builtin_amdgcn_mfma_f32_16x16x32_f16(aC, onesB,  e2, 0, 0, 0);
            d3 = __builtin_amdgcn_mfma_f32_16x16x32_f16(aD, bfPrev, d3, 0, 0, 0);
            e3 = __builtin_amdgcn_mfma_f32_16x16x32_f16(aD, onesB,  e3, 0, 0, 0);
            __builtin_amdgcn_s_setprio(0);
        }
        kfA = kfA2; kfB = kfB2; bfPrev = bfCur; bfCur = bf2;
    }
    // drain: MFMA the last chunk-pair (pv=24 wrote buf 0; bfPrev = V chunk 24)
    {
        const _Float16* rbuf = ptw;                   // (24 & 1) == 0
        f16x8 aA = *(const f16x8*)(rbuf + 0 * 648 + rof);
        f16x8 aB = *(const f16x8*)(rbuf + 1 * 648 + rof);
        f16x8 aC = *(const f16x8*)(rbuf + 2 * 648 + rof);
        f16x8 aD = *(const f16x8*)(rbuf + 3 * 648 + rof);
        __builtin_amdgcn_s_setprio(1);
        d0 = __builtin_amdgcn_mfma_f32_16x16x32_f16(aA, bfPrev, d0, 0, 0, 0);
        e0 = __builtin_amdgcn_mfma_f32_16x16x32_f16(aA, onesB,  e0, 0, 0, 0);
        d1 = __builtin_amdgcn_mfma_f32_16x16x32_f16(aB, bfPrev, d1, 0, 0, 0);
        e1 = __builtin_amdgcn_mfma_f32_16x16x32_f16(aB, onesB,  e1, 0, 0, 0);
        d2 = __builtin_amdgcn_mfma_f32_16x16x32_f16(aC, bfPrev, d2, 0, 0, 0);
        e2 = __builtin_amdgcn_mfma_f32_16x16x32_f16(aC, onesB,  e2, 0, 0, 0);
        d3 = __builtin_amdgcn_mfma_f32_16x16x32_f16(aD, bfPrev, d3, 0, 0, 0);
        e3 = __builtin_amdgcn_mfma_f32_16x16x32_f16(aD, onesB,  e3, 0, 0, 0);
        __builtin_amdgcn_s_setprio(0);
    }

    __syncthreads();                                  // B3: all waves done with ptile
    // ---- epilogue: out_v/ps -> ovh[g][q][m*8+h]; (q,g) of e_t[reg] == d_t[reg] ----
    _Float16* ovh = (_Float16*)(smem + UNI_OFF);
    {
        int mo = q15 * 8 + wave;                      // m = q15 (D col), h = wave
#pragma unroll
        for (int reg = 0; reg < 4; ++reg) {           // reg = g; q = 4*tile + rg
            float i0 = (e0[reg] > 0.0f) ? 1.0f / e0[reg] : 0.0f;
            float i1 = (e1[reg] > 0.0f) ? 1.0f / e1[reg] : 0.0f;
            float i2 = (e2[reg] > 0.0f) ? 1.0f / e2[reg] : 0.0f;
            float i3 = (e3[reg] > 0.0f) ? 1.0f / e3[reg] : 0.0f;
            ovh[(reg * 16 +      rg) * 136 + mo] = (_Float16)(d0[reg] * i0);
            ovh[(reg * 16 +  4 + rg) * 136 + mo] = (_Float16)(d1[reg] * i1);
            ovh[(reg * 16 +  8 + rg) * 136 + mo] = (_Float16)(d2[reg] * i2);
            ovh[(reg * 16 + 12 + rg) * 136 + mo] = (_Float16)(d3[reg] * i3);
        }
    }
    __syncthreads();                                  // B4: ovh ready

    // ---- output projection via MFMA: wave handles 2 (ob,g) tiles ----
#pragma unroll
    for (int tt2 = 0; tt2 < 2; ++tt2) {
        int tl = wave * 2 + tt2;
        int ob = tl >> 2, g = tl & 3;
        f32x4 dd = {0,0,0,0};
#pragma unroll
        for (int c = 0; c < 4; ++c) {
            f16x8 wa = *(const f16x8*)(Wfrag + ((size_t)((ob * 4 + c) * 64 + lane)) * 8);
            f16x8 vb = *(const f16x8*)(ovh + (g * 16 + q15) * 136 + c * 32 + rg * 8);
            dd = __builtin_amdgcn_mfma_f32_16x16x32_f16(wa, vb, dd, 0, 0, 0);
        }
#pragma unroll
        for (int reg = 0; reg < 4; ++reg) {
            int o = ob * 16 + rg * 4 + reg;           // D row
            out[((size_t)(b * 64 + o) * 4 + g) * NPOS + qt * 16 + q15] = dd[reg] + b_out[o];
        }
    }
}

extern "C" void kernel_launch(void* const* d_in, const int* in_sizes, int n_in,
                              void* d_out, int out_size, void* d_ws, size_t ws_size,
                              hipStream_t stream)
{
    const float* x     = (const float*)d_in[0];
    const float* wq    = (const float*)d_in[1];
    const float* bq    = (const float*)d_in[2];
    const float* wk    = (const float*)d_in[3];
    const float* bk    = (const float*)d_in[4];
    const float* wv    = (const float*)d_in[5];
    const float* bv    = (const float*)d_in[6];
    const float* w_out = (const float*)d_in[7];
    const float* b_out = (const float*)d_in[8];
    const float* rw1 = (const float*)d_in[9];
    const float* rb1 = (const float*)d_in[10];
    const float* rga = (const float*)d_in[11];
    const float* rbe = (const float*)d_in[12];
    const float* rw2 = (const float*)d_in[13];
    const float* rb2 = (const float*)d_in[14];
    const float* cw1 = (const float*)d_in[15];
    const float* cb1 = (const float*)d_in[16];
    const float* cga = (const float*)d_in[17];
    const float* cbe = (const float*)d_in[18];
    const float* cw2 = (const float*)d_in[19];
    const float* cb2 = (const float*)d_in[20];
    // d_in[21]/d_in[22] (ridx/cidx) unused: closed-form rotation indices.

    _Float16* Kfrag  = (_Float16*)d_ws;               // 32*49*64*8 = 802816 halves
    _Float16* Vfrag  = Kfrag + 802816;                // 32*25*64*8 = 409600
    _Float16* Wfrag  = Vfrag + 409600;                // 8192
    _Float16* Efrag  = Wfrag + 8192;                  // 16 frags x 64 x 8 = 8192

    prep_kernel<<<418, 256, 0, stream>>>(x, wk, bk, wv, bv, w_out,
                                         rw1, rb1, rga, rbe, rw2, rb2,
                                         cw1, cb1, cga, cbe, cw2, cb2,
                                         Kfrag, Vfrag, Wfrag, Efrag);
    attn_kernel<<<196, 512, 0, stream>>>(Kfrag, Vfrag, Wfrag, Efrag,
                                         x, wq, bq, b_out, (float*)d_out);
}